// Round 1
// baseline (184.175 us; speedup 1.0000x reference)
//
#include <hip/hip_runtime.h>
#include <hip/hip_bf16.h>

#define W0 0.4f
#define W1 1.6f

struct WS {
    double sum;                 // sum of per_elem terms
    unsigned long long correct; // count of round(p) == target
};

__global__ __launch_bounds__(256) void bce_reduce_kernel(
    const float* __restrict__ input,
    const int* __restrict__ target,
    WS* __restrict__ ws,
    int nvec)  // n/4
{
    const float4* in4 = reinterpret_cast<const float4*>(input);
    const int4*   tg4 = reinterpret_cast<const int4*>(target);

    float sum = 0.0f;
    unsigned int correct = 0;

    int stride = gridDim.x * blockDim.x;
    for (int i = blockIdx.x * blockDim.x + threadIdx.x; i < nvec; i += stride) {
        float4 p = in4[i];
        int4   t = tg4[i];

        // per_elem = t==1 ? log(p)*W1 : log(1-p)*W0
        {
            float lp = __logf(p.x), ln = __logf(1.0f - p.x);
            sum += (t.x == 1) ? lp * W1 : ln * W0;
            correct += (rintf(p.x) == (float)t.x) ? 1u : 0u;
        }
        {
            float lp = __logf(p.y), ln = __logf(1.0f - p.y);
            sum += (t.y == 1) ? lp * W1 : ln * W0;
            correct += (rintf(p.y) == (float)t.y) ? 1u : 0u;
        }
        {
            float lp = __logf(p.z), ln = __logf(1.0f - p.z);
            sum += (t.z == 1) ? lp * W1 : ln * W0;
            correct += (rintf(p.z) == (float)t.z) ? 1u : 0u;
        }
        {
            float lp = __logf(p.w), ln = __logf(1.0f - p.w);
            sum += (t.w == 1) ? lp * W1 : ln * W0;
            correct += (rintf(p.w) == (float)t.w) ? 1u : 0u;
        }
    }

    // wave-64 reduction
    #pragma unroll
    for (int off = 32; off > 0; off >>= 1) {
        sum     += __shfl_down(sum, off, 64);
        correct += __shfl_down(correct, off, 64);
    }

    // block reduction across 4 waves via LDS
    __shared__ float  s_sum[4];
    __shared__ unsigned int s_cnt[4];
    int lane = threadIdx.x & 63;
    int wave = threadIdx.x >> 6;
    if (lane == 0) { s_sum[wave] = sum; s_cnt[wave] = correct; }
    __syncthreads();
    if (threadIdx.x == 0) {
        float bs = s_sum[0] + s_sum[1] + s_sum[2] + s_sum[3];
        unsigned int bc = s_cnt[0] + s_cnt[1] + s_cnt[2] + s_cnt[3];
        atomicAdd(&ws->sum, (double)bs);
        atomicAdd(&ws->correct, (unsigned long long)bc);
    }
}

__global__ void bce_finalize_kernel(const WS* __restrict__ ws,
                                    float* __restrict__ out, int n)
{
    if (threadIdx.x == 0) {
        double inv_n = 1.0 / (double)n;
        out[0] = (float)(-ws->sum * inv_n);
        out[1] = (float)((double)ws->correct * inv_n);
    }
}

extern "C" void kernel_launch(void* const* d_in, const int* in_sizes, int n_in,
                              void* d_out, int out_size, void* d_ws, size_t ws_size,
                              hipStream_t stream) {
    const float* input  = (const float*)d_in[0];
    const int*   target = (const int*)d_in[1];
    float* out = (float*)d_out;
    int n = in_sizes[0];
    int nvec = n >> 2;

    WS* ws = (WS*)d_ws;
    hipMemsetAsync(ws, 0, sizeof(WS), stream);

    // 2048 blocks x 256 threads x 4 elems = 2M elems per pass -> 8 passes over 16M
    int block = 256;
    int grid = 2048;
    bce_reduce_kernel<<<grid, block, 0, stream>>>(input, target, ws, nvec);
    bce_finalize_kernel<<<1, 64, 0, stream>>>(ws, out, n);
}

// Round 2
// 144.258 us; speedup vs baseline: 1.2767x; 1.2767x over previous
//
#include <hip/hip_runtime.h>
#include <hip/hip_bf16.h>

#define W0 0.4f
#define W1 1.6f

// Each block: 256 threads x 4 float4 vectors = 4096 elements.
// Grid = n / 4096. Every block writes its partial -> no ws zero-init needed.

__global__ __launch_bounds__(256) void bce_reduce_kernel(
    const float4* __restrict__ in4,
    const int4* __restrict__ tg4,
    float* __restrict__ psum,
    unsigned int* __restrict__ pcnt)
{
    const int base = blockIdx.x * 1024 + threadIdx.x;

    // Issue all 8 loads up front (128 B/thread in flight).
    float4 p0 = in4[base];
    float4 p1 = in4[base + 256];
    float4 p2 = in4[base + 512];
    float4 p3 = in4[base + 768];
    int4 t0 = tg4[base];
    int4 t1 = tg4[base + 256];
    int4 t2 = tg4[base + 512];
    int4 t3 = tg4[base + 768];

    float sum = 0.0f;
    unsigned int correct = 0;

#define ELEM(P, T)                                                   \
    {                                                                \
        bool pos = ((T) == 1);                                       \
        float x = pos ? (P) : (1.0f - (P));                          \
        float w = pos ? W1 : W0;                                     \
        sum = __builtin_fmaf(__logf(x), w, sum);                     \
        correct += (rintf(P) == (float)(T)) ? 1u : 0u;               \
    }

    ELEM(p0.x, t0.x) ELEM(p0.y, t0.y) ELEM(p0.z, t0.z) ELEM(p0.w, t0.w)
    ELEM(p1.x, t1.x) ELEM(p1.y, t1.y) ELEM(p1.z, t1.z) ELEM(p1.w, t1.w)
    ELEM(p2.x, t2.x) ELEM(p2.y, t2.y) ELEM(p2.z, t2.z) ELEM(p2.w, t2.w)
    ELEM(p3.x, t3.x) ELEM(p3.y, t3.y) ELEM(p3.z, t3.z) ELEM(p3.w, t3.w)
#undef ELEM

    // wave-64 reduction
    #pragma unroll
    for (int off = 32; off > 0; off >>= 1) {
        sum     += __shfl_down(sum, off, 64);
        correct += __shfl_down(correct, off, 64);
    }

    __shared__ float s_sum[4];
    __shared__ unsigned int s_cnt[4];
    const int lane = threadIdx.x & 63;
    const int wave = threadIdx.x >> 6;
    if (lane == 0) { s_sum[wave] = sum; s_cnt[wave] = correct; }
    __syncthreads();
    if (threadIdx.x == 0) {
        float bs = s_sum[0] + s_sum[1] + s_sum[2] + s_sum[3];
        unsigned int bc = s_cnt[0] + s_cnt[1] + s_cnt[2] + s_cnt[3];
        psum[blockIdx.x] = bs;
        pcnt[blockIdx.x] = bc;
    }
}

__global__ __launch_bounds__(1024) void bce_finalize_kernel(
    const float* __restrict__ psum,
    const unsigned int* __restrict__ pcnt,
    float* __restrict__ out, int nblocks, int n)
{
    const int tid = threadIdx.x;
    double s = 0.0;
    unsigned long long c = 0;
    for (int k = tid; k < nblocks; k += 1024) {
        s += (double)psum[k];
        c += (unsigned long long)pcnt[k];
    }
    #pragma unroll
    for (int off = 32; off > 0; off >>= 1) {
        s += __shfl_down(s, off, 64);
        c += __shfl_down(c, off, 64);
    }
    __shared__ double sh_s[16];
    __shared__ unsigned long long sh_c[16];
    const int lane = tid & 63;
    const int wave = tid >> 6;
    if (lane == 0) { sh_s[wave] = s; sh_c[wave] = c; }
    __syncthreads();
    if (tid == 0) {
        double ts = 0.0;
        unsigned long long tc = 0;
        for (int w = 0; w < 16; ++w) { ts += sh_s[w]; tc += sh_c[w]; }
        double inv_n = 1.0 / (double)n;
        out[0] = (float)(-ts * inv_n);
        out[1] = (float)((double)tc * inv_n);
    }
}

extern "C" void kernel_launch(void* const* d_in, const int* in_sizes, int n_in,
                              void* d_out, int out_size, void* d_ws, size_t ws_size,
                              hipStream_t stream) {
    const float4* in4 = (const float4*)d_in[0];
    const int4*   tg4 = (const int4*)d_in[1];
    float* out = (float*)d_out;
    int n = in_sizes[0];
    int nblocks = n >> 12;  // 4096 elems per block

    float* psum = (float*)d_ws;
    unsigned int* pcnt = (unsigned int*)((char*)d_ws + (size_t)nblocks * sizeof(float));

    bce_reduce_kernel<<<nblocks, 256, 0, stream>>>(in4, tg4, psum, pcnt);
    bce_finalize_kernel<<<1, 1024, 0, stream>>>(psum, pcnt, out, nblocks, n);
}